// Round 14
// baseline (522.304 us; speedup 1.0000x reference)
//
#include <hip/hip_runtime.h>
#include <hip/hip_bf16.h>

typedef __hip_bfloat16 bf16;
typedef __attribute__((ext_vector_type(8))) short s8v;
typedef __attribute__((ext_vector_type(4))) float f4v;
typedef __attribute__((ext_vector_type(2))) float f2v;
typedef unsigned short u16;
typedef unsigned int u32;
typedef unsigned char u8;

#define NN 32768
#define NE 524288
#define D 128
#define H 4
#define C 32
#define R 5
#define BS 8192

__device__ __forceinline__ u16 f2bs(float x) { bf16 h = __float2bfloat16(x); return *(u16*)&h; }
__device__ __forceinline__ float bflo(u32 u) { return __uint_as_float(u << 16); }
__device__ __forceinline__ float bfhi(u32 u) { return __uint_as_float(u & 0xffff0000u); }
// fast bf16 pair pack: round-half-up (+0x8000) then byte-perm; 3 VALU instrs
__device__ __forceinline__ u32 pack2r(float a, float b) {
    u32 ua = __float_as_uint(a) + 0x8000u;
    u32 ub = __float_as_uint(b) + 0x8000u;
    return __builtin_amdgcn_perm(ub, ua, 0x07060302u);   // lo16=hi(a), hi16=hi(b)
}
__device__ __forceinline__ u16 rnd16(float a) {
    return (u16)((__float_as_uint(a) + 0x8000u) >> 16);
}
__device__ __forceinline__ float gelu_f(float x) {   // exact (epilogue use)
    return 0.5f * x * (1.f + erff(x * 0.7071067811865475f));
}
// fast gelu: x * sigmoid(2*sqrt(2/pi)*(x + 0.044715 x^3)); |err| < ~1e-3
__device__ __forceinline__ float gelu_fast(float x) {
    float x2 = x * x;
    float u = x * fmaf(0.0713548162f, x2, 1.5957691216f);
    return x * __builtin_amdgcn_rcpf(1.f + __expf(-u));
}

// ---- static device scratch ----
__device__ u16      g_x[NN * D];          // bf16 working activations
__device__ float    g_araw[NE * H];       // exp(logit), CSR-position indexed
__device__ u8       g_P8[R * NN * D];     // fp8 e4m3: x @ Rtop[r]   (logit path)
__device__ u8       g_Q8[R * NN * D];     // fp8 e4m3: x @ Rbot[r]   (logit path)
__device__ u16      g_xl[NN * D];         // bf16: x @ Wl + bl       (value path)
__device__ u8       g_xl8[NN * D];        // fp8 copy of xl          (logit path)
__device__ u16      g_WnF[26 * 2048 * 8]; // bf16 weights, MFMA B-frag order
__device__ int      g_cnt[NN];            // CSR: in-degree counts
__device__ int      g_cur[NN];            // CSR: scatter cursors
__device__ int      g_off[NN + 1];        // CSR: row offsets (by dst)
__device__ int      g_se[NE];             // CSR-ordered src node ids
__device__ int      g_de[NE];             // CSR-ordered dst node ids
__device__ int      g_re[NE];             // CSR-ordered relation ids

__global__ void k_cvt(const float* __restrict__ e) {
    int i = blockIdx.x * 256 + threadIdx.x;   // NN*D/2 threads
    float2 v = *(const float2*)&e[(size_t)i * 2];
    ((u32*)g_x)[i] = pack2r(v.x, v.y);
}

// ---- CSR build (edge list identical for both layers: build once) ----
__global__ void k_zcnt() {
    int i = blockIdx.x * 256 + threadIdx.x;   // NN threads
    g_cnt[i] = 0; g_cur[i] = 0;
}
__global__ void k_count(const int* __restrict__ ei) {
    int i = blockIdx.x * 256 + threadIdx.x;   // NE threads
    atomicAdd(&g_cnt[ei[NE + i]], 1);
}
__global__ void k_scan() {   // 1 block, 1024 threads, 32 elems each
    __shared__ int sums[1024];
    const int t = threadIdx.x;
    const int base = t * 32;
    int local[32];
    int s = 0;
#pragma unroll
    for (int i = 0; i < 32; ++i) { local[i] = s; s += g_cnt[base + i]; }
    sums[t] = s;
    __syncthreads();
    for (int off = 1; off < 1024; off <<= 1) {
        int v = (t >= off) ? sums[t - off] : 0;
        __syncthreads();
        sums[t] += v;
        __syncthreads();
    }
    int chunkoff = (t == 0) ? 0 : sums[t - 1];
#pragma unroll
    for (int i = 0; i < 32; ++i) g_off[base + i] = chunkoff + local[i];
    if (t == 1023) g_off[NN] = sums[1023];
}
__global__ void k_scatter(const int* __restrict__ ei, const int* __restrict__ et) {
    int i = blockIdx.x * 256 + threadIdx.x;   // NE threads
    int d = ei[NE + i];
    int pos = g_off[d] + atomicAdd(&g_cur[d], 1);
    g_se[pos] = ei[i];
    g_de[pos] = d;
    g_re[pos] = et[i];
}

// ---- weights -> bf16 MFMA B-fragment order (one layer, 13 matrices) ----
__global__ void k_prep(const float* __restrict__ Wl, const float* __restrict__ Rm,
                       const float* __restrict__ We, const float* __restrict__ Ow,
                       int base) {
    int f = blockIdx.x * 256 + threadIdx.x;   // frag id 0..2047
    int y = blockIdx.y;
    const float* src;
    if (y == 0) src = Wl;
    else if (y <= R) src = Rm + (size_t)(y - 1) * 2 * D * D;
    else if (y <= 2 * R) src = Rm + (size_t)(y - 1 - R) * 2 * D * D + D * D;
    else if (y == 11) src = We;
    else src = Ow;
    int lane = f & 63, nt = (f >> 6) & 7, s = f >> 9;
    int n = nt * 16 + (lane & 15);
    int ks = s * 32 + (lane >> 4) * 8;
    u16 tmp[8];
#pragma unroll
    for (int j = 0; j < 8; ++j) tmp[j] = f2bs(src[(size_t)(ks + j) * D + n]);
    *(uint4*)&g_WnF[((size_t)(base + y) * 2048 + f) * 8] = *(uint4*)tmp;
}

// ---- node transforms (MFMA, LDS-free): xl (bf16+fp8) / P[r],Q[r] (fp8) ----
__global__ __launch_bounds__(256) void k_node(const float* __restrict__ bl, int wbase) {
    const int tid = threadIdx.x;
    const int n0 = blockIdx.x * 64;
    const int wsel = blockIdx.y;
    const int l = tid & 63, w = tid >> 6;
    const int mrow = l & 15, quad = l >> 4;
    const u16* xrow = g_x + (size_t)(n0 + w * 16 + mrow) * D;
    const u16* BF = g_WnF + (size_t)(wbase + wsel) * 2048 * 8;

    f4v acc[8];
#pragma unroll
    for (int nt = 0; nt < 8; ++nt) acc[nt] = (f4v){0.f, 0.f, 0.f, 0.f};
#pragma unroll
    for (int s = 0; s < 4; ++s) {
        s8v a = *(const s8v*)&xrow[s * 32 + quad * 8];
#pragma unroll
        for (int nt = 0; nt < 8; ++nt) {
            s8v b = *(const s8v*)&BF[(size_t)((s * 8 + nt) * 64 + l) * 8];
            acc[nt] = __builtin_amdgcn_mfma_f32_16x16x32_bf16(a, b, acc[nt], 0, 0, 0);
        }
    }

    if (wsel == 0) {
#pragma unroll
        for (int nt = 0; nt < 8; ++nt) {
            int col = nt * 16 + mrow;
            float bias = bl[col];
            float v[4];
#pragma unroll
            for (int r = 0; r < 4; ++r) v[r] = acc[nt][r] + bias;
#pragma unroll
            for (int r = 0; r < 4; ++r) {
                int row = n0 + w * 16 + quad * 4 + r;
                g_xl[(size_t)row * D + col] = rnd16(v[r]);
            }
#pragma unroll
            for (int r = 0; r < 4; r += 2) {
                u32 pk = __builtin_amdgcn_cvt_pk_fp8_f32(v[r], v[r + 1], 0, false);
                int row = n0 + w * 16 + quad * 4 + r;
                g_xl8[(size_t)row * D + col] = (u8)(pk & 0xffu);
                g_xl8[(size_t)(row + 1) * D + col] = (u8)((pk >> 8) & 0xffu);
            }
        }
    } else {
        u8* out8 = (wsel <= R) ? g_P8 + (size_t)(wsel - 1) * NN * D
                               : g_Q8 + (size_t)(wsel - 1 - R) * NN * D;
#pragma unroll
        for (int nt = 0; nt < 8; ++nt) {
            int col = nt * 16 + mrow;
#pragma unroll
            for (int r = 0; r < 4; r += 2) {
                u32 pk = __builtin_amdgcn_cvt_pk_fp8_f32(acc[nt][r], acc[nt][r + 1], 0, false);
                int row = n0 + w * 16 + quad * 4 + r;
                out8[(size_t)row * D + col] = (u8)(pk & 0xffu);
                out8[(size_t)(row + 1) * D + col] = (u8)((pk >> 8) & 0xffu);
            }
        }
    }
}

// ---- fused edge kernel: 2 tiles/wave, all-fp8 logit gathers, stores exp(logit) ----
// block = 128 CSR positions (4 waves x 2 x 16 edges); grid NE/128
__global__ __launch_bounds__(256) void k_edge(const float* __restrict__ att, int wbase) {
    const int tid = threadIdx.x;
    const int e0 = blockIdx.x * 128;
    const int l = tid & 63, w = tid >> 6;
    const int mrow = l & 15, quad = l >> 4;
    const u16* BF = g_WnF + (size_t)(wbase + 11) * 2048 * 8;

    // identity B-frags: Bev for even nt (k_local == mrow), Bod for odd (== mrow+16)
    union { u32 u[4]; s8v v; } bev, bod;
#pragma unroll
    for (int jp = 0; jp < 4; ++jp) {
        int j0 = quad * 8 + jp * 2, j1 = j0 + 1;
        bev.u[jp] = ((j0 == mrow) ? 0x3F80u : 0u) | ((j1 == mrow) ? 0x3F800000u : 0u);
        bod.u[jp] = ((j0 == mrow + 16) ? 0x3F80u : 0u) | ((j1 == mrow + 16) ? 0x3F800000u : 0u);
    }

    // metadata + raw gathers for BOTH tiles up front (max loads in flight)
    int sei[2], dei[2], rei[2];
#pragma unroll
    for (int t = 0; t < 2; ++t) {
        int p = e0 + t * 64 + w * 16 + mrow;
        sei[t] = g_se[p]; dei[t] = g_de[p]; rei[t] = g_re[p];
    }
    uint2 pu[2][4], qu[2][4], su[2][4], du[2][4];
#pragma unroll
    for (int t = 0; t < 2; ++t) {
        const u8* Pr = g_P8 + ((size_t)rei[t] * NN + sei[t]) * D;
        const u8* Qr = g_Q8 + ((size_t)rei[t] * NN + dei[t]) * D;
        const u8* Xs = g_xl8 + (size_t)sei[t] * D;
        const u8* Xd = g_xl8 + (size_t)dei[t] * D;
#pragma unroll
        for (int s = 0; s < 4; ++s) {
            int c0 = s * 32 + quad * 8;
            pu[t][s] = *(const uint2*)&Pr[c0];
            qu[t][s] = *(const uint2*)&Qr[c0];
            su[t][s] = *(const uint2*)&Xs[c0];
            du[t][s] = *(const uint2*)&Xd[c0];
        }
    }

#pragma unroll
    for (int t = 0; t < 2; ++t) {
        union { u32 u[4]; s8v v; } af[4], xf[4];
#pragma unroll
        for (int s = 0; s < 4; ++s) {
            f2v p0 = __builtin_amdgcn_cvt_pk_f32_fp8(pu[t][s].x, false);
            f2v p1 = __builtin_amdgcn_cvt_pk_f32_fp8(pu[t][s].x, true);
            f2v p2 = __builtin_amdgcn_cvt_pk_f32_fp8(pu[t][s].y, false);
            f2v p3 = __builtin_amdgcn_cvt_pk_f32_fp8(pu[t][s].y, true);
            f2v q0 = __builtin_amdgcn_cvt_pk_f32_fp8(qu[t][s].x, false);
            f2v q1 = __builtin_amdgcn_cvt_pk_f32_fp8(qu[t][s].x, true);
            f2v q2 = __builtin_amdgcn_cvt_pk_f32_fp8(qu[t][s].y, false);
            f2v q3 = __builtin_amdgcn_cvt_pk_f32_fp8(qu[t][s].y, true);
            af[s].u[0] = pack2r(gelu_fast(p0.x + q0.x), gelu_fast(p0.y + q0.y));
            af[s].u[1] = pack2r(gelu_fast(p1.x + q1.x), gelu_fast(p1.y + q1.y));
            af[s].u[2] = pack2r(gelu_fast(p2.x + q2.x), gelu_fast(p2.y + q2.y));
            af[s].u[3] = pack2r(gelu_fast(p3.x + q3.x), gelu_fast(p3.y + q3.y));
            f2v s0 = __builtin_amdgcn_cvt_pk_f32_fp8(su[t][s].x, false);
            f2v s1 = __builtin_amdgcn_cvt_pk_f32_fp8(su[t][s].x, true);
            f2v s2 = __builtin_amdgcn_cvt_pk_f32_fp8(su[t][s].y, false);
            f2v s3 = __builtin_amdgcn_cvt_pk_f32_fp8(su[t][s].y, true);
            f2v d0 = __builtin_amdgcn_cvt_pk_f32_fp8(du[t][s].x, false);
            f2v d1 = __builtin_amdgcn_cvt_pk_f32_fp8(du[t][s].x, true);
            f2v d2 = __builtin_amdgcn_cvt_pk_f32_fp8(du[t][s].y, false);
            f2v d3 = __builtin_amdgcn_cvt_pk_f32_fp8(du[t][s].y, true);
            xf[s].u[0] = pack2r(s0.x + d0.x, s0.y + d0.y);
            xf[s].u[1] = pack2r(s1.x + d1.x, s1.y + d1.y);
            xf[s].u[2] = pack2r(s2.x + d2.x, s2.y + d2.y);
            xf[s].u[3] = pack2r(s3.x + d3.x, s3.y + d3.y);
        }

        f4v acc[8];
#pragma unroll
        for (int nt = 0; nt < 8; ++nt) acc[nt] = (f4v){0.f, 0.f, 0.f, 0.f};
#pragma unroll
        for (int s = 0; s < 4; ++s) {
#pragma unroll
            for (int nt = 0; nt < 8; ++nt) {
                s8v b = *(const s8v*)&BF[(size_t)((s * 8 + nt) * 64 + l) * 8];
                acc[nt] = __builtin_amdgcn_mfma_f32_16x16x32_bf16(af[s].v, b, acc[nt], 0, 0, 0);
            }
            acc[2 * s]     = __builtin_amdgcn_mfma_f32_16x16x32_bf16(xf[s].v, bev.v, acc[2 * s], 0, 0, 0);
            acc[2 * s + 1] = __builtin_amdgcn_mfma_f32_16x16x32_bf16(xf[s].v, bod.v, acc[2 * s + 1], 0, 0, 0);
        }

        // epilogue in C-layout: edge = t*64 + w*16 + quad*4 + r, col = nt*16 + mrow
        float hsum[4][4];
#pragma unroll
        for (int r = 0; r < 4; ++r)
#pragma unroll
            for (int h = 0; h < 4; ++h) hsum[r][h] = 0.f;
#pragma unroll
        for (int nt = 0; nt < 8; ++nt) {
            int col = nt * 16 + mrow;
            float av = att[col];
            int h = nt >> 1;
#pragma unroll
            for (int r = 0; r < 4; ++r) {
                float m = acc[nt][r];
                float lr = m > 0.f ? m : 0.2f * m;
                hsum[r][h] = fmaf(lr, av, hsum[r][h]);
            }
        }
#pragma unroll
        for (int r = 0; r < 4; ++r)
#pragma unroll
            for (int h = 0; h < 4; ++h) {
                float v = hsum[r][h];
                v += __shfl_xor(v, 1); v += __shfl_xor(v, 2);
                v += __shfl_xor(v, 4); v += __shfl_xor(v, 8);
                hsum[r][h] = v;
            }
        if ((mrow & 3) == 0) {   // store exp(logit) directly
            int r = mrow >> 2;
            float4 v = make_float4(__expf(fminf(hsum[r][0], 80.f)),
                                   __expf(fminf(hsum[r][1], 80.f)),
                                   __expf(fminf(hsum[r][2], 80.f)),
                                   __expf(fminf(hsum[r][3], 80.f)));
            *(float4*)&g_araw[(size_t)(e0 + t * 64 + w * 16 + quad * 4 + r) * H] = v;
        }
    }
}

// ---- fused gather: single-pass aggregate over pre-computed exp(logit) ----
// one wave per dst; block 256 = 4 dsts; grid NN/4
__global__ __launch_bounds__(256) void k_gath(const float* __restrict__ bias,
                                              int do_gelu) {
    const int lane = threadIdx.x & 63;
    const int d = blockIdx.x * 4 + (threadIdx.x >> 6);
    const int off = g_off[d];
    const int deg = g_off[d + 1] - off;
    const int h = lane >> 4;        // head for cols 2*lane, 2*lane+1

    const int* __restrict__ srcs = g_se + off;
    const float* __restrict__ ar = g_araw + (size_t)off * H + h;
    float a0 = 0.f, a1 = 0.f, dn = 0.f;
    int p = 0;
    for (; p + 4 <= deg; p += 4) {
        int s0 = srcs[p], s1 = srcs[p + 1], s2 = srcs[p + 2], s3 = srcs[p + 3];
        u32 w0 = *(const u32*)&g_xl[(size_t)s0 * D + lane * 2];
        u32 w1 = *(const u32*)&g_xl[(size_t)s1 * D + lane * 2];
        u32 w2 = *(const u32*)&g_xl[(size_t)s2 * D + lane * 2];
        u32 w3 = *(const u32*)&g_xl[(size_t)s3 * D + lane * 2];
        float c0 = ar[(p + 0) * H];
        float c1 = ar[(p + 1) * H];
        float c2 = ar[(p + 2) * H];
        float c3 = ar[(p + 3) * H];
        dn += (c0 + c1) + (c2 + c3);
        a0 = fmaf(bflo(w0), c0, a0); a1 = fmaf(bfhi(w0), c0, a1);
        a0 = fmaf(bflo(w1), c1, a0); a1 = fmaf(bfhi(w1), c1, a1);
        a0 = fmaf(bflo(w2), c2, a0); a1 = fmaf(bfhi(w2), c2, a1);
        a0 = fmaf(bflo(w3), c3, a0); a1 = fmaf(bfhi(w3), c3, a1);
    }
    for (; p < deg; ++p) {
        int s = srcs[p];
        u32 w = *(const u32*)&g_xl[(size_t)s * D + lane * 2];
        float cf = ar[p * H];
        dn += cf;
        a0 = fmaf(bflo(w), cf, a0);
        a1 = fmaf(bfhi(w), cf, a1);
    }
    const float inv = __builtin_amdgcn_rcpf(dn + 1e-16f);
    float v0 = a0 * inv + bias[lane * 2];
    float v1 = a1 * inv + bias[lane * 2 + 1];
    if (do_gelu) { v0 = gelu_f(v0); v1 = gelu_f(v1); }
    ((u32*)g_x)[(size_t)d * (D / 2) + lane] = pack2r(v0, v1);
}

// ---- output head (MFMA, LDS-free): y = x[:BS]@out_w + out_b; LayerNorm ----
__global__ __launch_bounds__(256) void k_head(const float* __restrict__ ob,
                                              const float* __restrict__ g,
                                              const float* __restrict__ b,
                                              float* __restrict__ out) {
    const int tid = threadIdx.x;
    const int r0 = blockIdx.x * 64;
    const int l = tid & 63, w = tid >> 6;
    const int mrow = l & 15, quad = l >> 4;
    const u16* xrow = g_x + (size_t)(r0 + w * 16 + mrow) * D;
    const u16* BF = g_WnF + (size_t)12 * 2048 * 8;

    f4v acc[8];
#pragma unroll
    for (int nt = 0; nt < 8; ++nt) acc[nt] = (f4v){0.f, 0.f, 0.f, 0.f};
#pragma unroll
    for (int s = 0; s < 4; ++s) {
        s8v a = *(const s8v*)&xrow[s * 32 + quad * 8];
#pragma unroll
        for (int nt = 0; nt < 8; ++nt) {
            s8v bb = *(const s8v*)&BF[(size_t)((s * 8 + nt) * 64 + l) * 8];
            acc[nt] = __builtin_amdgcn_mfma_f32_16x16x32_bf16(a, bb, acc[nt], 0, 0, 0);
        }
    }

    float sum[4] = {0.f, 0.f, 0.f, 0.f};
#pragma unroll
    for (int nt = 0; nt < 8; ++nt) {
        float obv = ob[nt * 16 + mrow];
#pragma unroll
        for (int r = 0; r < 4; ++r) {
            acc[nt][r] += obv;
            sum[r] += acc[nt][r];
        }
    }
    float mu[4];
#pragma unroll
    for (int r = 0; r < 4; ++r) {
        float s = sum[r];
        s += __shfl_xor(s, 1); s += __shfl_xor(s, 2);
        s += __shfl_xor(s, 4); s += __shfl_xor(s, 8);
        mu[r] = s * (1.f / D);
    }
    float sq[4] = {0.f, 0.f, 0.f, 0.f};
#pragma unroll
    for (int nt = 0; nt < 8; ++nt)
#pragma unroll
        for (int r = 0; r < 4; ++r) {
            float dv = acc[nt][r] - mu[r];
            sq[r] += dv * dv;
        }
    float rs[4];
#pragma unroll
    for (int r = 0; r < 4; ++r) {
        float s = sq[r];
        s += __shfl_xor(s, 1); s += __shfl_xor(s, 2);
        s += __shfl_xor(s, 4); s += __shfl_xor(s, 8);
        rs[r] = rsqrtf(s * (1.f / D) + 1e-12f);
    }
#pragma unroll
    for (int nt = 0; nt < 8; ++nt) {
        int col = nt * 16 + mrow;
        float gv = g[col], bv = b[col];
#pragma unroll
        for (int r = 0; r < 4; ++r) {
            int row = r0 + w * 16 + quad * 4 + r;
            out[(size_t)row * D + col] = (acc[nt][r] - mu[r]) * rs[r] * gv + bv;
        }
    }
}

extern "C" void kernel_launch(void* const* d_in, const int* in_sizes, int n_in,
                              void* d_out, int out_size, void* d_ws, size_t ws_size,
                              hipStream_t stream) {
    (void)in_sizes; (void)n_in; (void)out_size; (void)d_ws; (void)ws_size;
    const float* embs = (const float*)d_in[0];
    const int*   ei   = (const int*)d_in[1];
    const int*   et   = (const int*)d_in[2];
    const float* rel  = (const float*)d_in[3];
    const float* wl[2]   = { (const float*)d_in[4],  (const float*)d_in[9]  };
    const float* bl[2]   = { (const float*)d_in[5],  (const float*)d_in[10] };
    const float* we[2]   = { (const float*)d_in[6],  (const float*)d_in[11] };
    const float* attw[2] = { (const float*)d_in[7],  (const float*)d_in[12] };
    const float* bs[2]   = { (const float*)d_in[8],  (const float*)d_in[13] };
    const float* ow  = (const float*)d_in[14];
    const float* ob  = (const float*)d_in[15];
    const float* lng = (const float*)d_in[16];
    const float* lnb = (const float*)d_in[17];
    float* out = (float*)d_out;

    k_cvt<<<NN * D / 512, 256, 0, stream>>>(embs);

    // weight prep for BOTH layers up front (overlaps CSR build)
    for (int l = 0; l < 2; ++l) {
        const float* Rm = rel + (size_t)l * R * 2 * D * D;
        k_prep<<<dim3(2048 / 256, 13), 256, 0, stream>>>(wl[l], Rm, we[l], ow, l * 13);
    }

    // CSR by dst (edge list shared by both layers)
    k_zcnt<<<NN / 256, 256, 0, stream>>>();
    k_count<<<NE / 256, 256, 0, stream>>>(ei);
    k_scan<<<1, 1024, 0, stream>>>();
    k_scatter<<<NE / 256, 256, 0, stream>>>(ei, et);

    for (int l = 0; l < 2; ++l) {
        k_node<<<dim3(NN / 64, 11), 256, 0, stream>>>(bl[l], l * 13);
        k_edge<<<NE / 128, 256, 0, stream>>>(attw[l], l * 13);
        k_gath<<<NN / 4, 256, 0, stream>>>(bs[l], l == 0 ? 1 : 0);
    }

    k_head<<<BS / 64, 256, 0, stream>>>(ob, lng, lnb, out);
}

// Round 15
// 496.165 us; speedup vs baseline: 1.0527x; 1.0527x over previous
//
#include <hip/hip_runtime.h>
#include <hip/hip_bf16.h>

typedef __hip_bfloat16 bf16;
typedef __attribute__((ext_vector_type(8))) short s8v;
typedef __attribute__((ext_vector_type(4))) float f4v;
typedef __attribute__((ext_vector_type(2))) float f2v;
typedef unsigned short u16;
typedef unsigned int u32;
typedef unsigned char u8;

#define NN 32768
#define NE 524288
#define D 128
#define H 4
#define C 32
#define R 5
#define BS 8192

__device__ __forceinline__ u16 f2bs(float x) { bf16 h = __float2bfloat16(x); return *(u16*)&h; }
__device__ __forceinline__ float bflo(u32 u) { return __uint_as_float(u << 16); }
__device__ __forceinline__ float bfhi(u32 u) { return __uint_as_float(u & 0xffff0000u); }
// fast bf16 pair pack: round-half-up (+0x8000) then byte-perm; 3 VALU instrs
__device__ __forceinline__ u32 pack2r(float a, float b) {
    u32 ua = __float_as_uint(a) + 0x8000u;
    u32 ub = __float_as_uint(b) + 0x8000u;
    return __builtin_amdgcn_perm(ub, ua, 0x07060302u);   // lo16=hi(a), hi16=hi(b)
}
__device__ __forceinline__ u16 rnd16(float a) {
    return (u16)((__float_as_uint(a) + 0x8000u) >> 16);
}
__device__ __forceinline__ float gelu_f(float x) {   // exact (epilogue use)
    return 0.5f * x * (1.f + erff(x * 0.7071067811865475f));
}
// fast gelu: x * sigmoid(2*sqrt(2/pi)*(x + 0.044715 x^3)); |err| < ~1e-3
__device__ __forceinline__ float gelu_fast(float x) {
    float x2 = x * x;
    float u = x * fmaf(0.0713548162f, x2, 1.5957691216f);
    return x * __builtin_amdgcn_rcpf(1.f + __expf(-u));
}

// ---- static device scratch ----
__device__ u16      g_x[NN * D];          // bf16 working activations
__device__ float    g_araw[NE * H];       // exp(logit), CSR-position indexed
__device__ u8       g_P8[R * NN * D];     // fp8 e4m3: x @ Rtop[r]   (logit path)
__device__ u8       g_Q8[R * NN * D];     // fp8 e4m3: x @ Rbot[r]   (logit path)
__device__ u16      g_xl[NN * D];         // bf16: x @ Wl + bl       (value path)
__device__ u8       g_xl8[NN * D];        // fp8 copy of xl          (logit path)
__device__ u16      g_WnF[26 * 2048 * 8]; // bf16 weights, MFMA B-frag order
__device__ int      g_cnt[NN];            // CSR: in-degree counts
__device__ int      g_cur[NN];            // CSR: scatter cursors
__device__ int      g_off[NN + 1];        // CSR: row offsets (by dst)
__device__ int      g_se[NE];             // CSR-ordered src node ids
__device__ int      g_de[NE];             // CSR-ordered dst node ids
__device__ int      g_re[NE];             // CSR-ordered relation ids

__global__ void k_cvt(const float* __restrict__ e) {
    int i = blockIdx.x * 256 + threadIdx.x;   // NN*D/2 threads
    float2 v = *(const float2*)&e[(size_t)i * 2];
    ((u32*)g_x)[i] = pack2r(v.x, v.y);
}

// ---- CSR build (edge list identical for both layers: build once) ----
__global__ void k_zcnt() {
    int i = blockIdx.x * 256 + threadIdx.x;   // NN threads
    g_cnt[i] = 0; g_cur[i] = 0;
}
__global__ void k_count(const int* __restrict__ ei) {
    int i = blockIdx.x * 256 + threadIdx.x;   // NE threads
    atomicAdd(&g_cnt[ei[NE + i]], 1);
}
__global__ void k_scan() {   // 1 block, 1024 threads, 32 elems each
    __shared__ int sums[1024];
    const int t = threadIdx.x;
    const int base = t * 32;
    int local[32];
    int s = 0;
#pragma unroll
    for (int i = 0; i < 32; ++i) { local[i] = s; s += g_cnt[base + i]; }
    sums[t] = s;
    __syncthreads();
    for (int off = 1; off < 1024; off <<= 1) {
        int v = (t >= off) ? sums[t - off] : 0;
        __syncthreads();
        sums[t] += v;
        __syncthreads();
    }
    int chunkoff = (t == 0) ? 0 : sums[t - 1];
#pragma unroll
    for (int i = 0; i < 32; ++i) g_off[base + i] = chunkoff + local[i];
    if (t == 1023) g_off[NN] = sums[1023];
}
__global__ void k_scatter(const int* __restrict__ ei, const int* __restrict__ et) {
    int i = blockIdx.x * 256 + threadIdx.x;   // NE threads
    int d = ei[NE + i];
    int pos = g_off[d] + atomicAdd(&g_cur[d], 1);
    g_se[pos] = ei[i];
    g_de[pos] = d;
    g_re[pos] = et[i];
}

// ---- weights -> bf16 MFMA B-fragment order (one layer, 13 matrices) ----
__global__ void k_prep(const float* __restrict__ Wl, const float* __restrict__ Rm,
                       const float* __restrict__ We, const float* __restrict__ Ow,
                       int base) {
    int f = blockIdx.x * 256 + threadIdx.x;   // frag id 0..2047
    int y = blockIdx.y;
    const float* src;
    if (y == 0) src = Wl;
    else if (y <= R) src = Rm + (size_t)(y - 1) * 2 * D * D;
    else if (y <= 2 * R) src = Rm + (size_t)(y - 1 - R) * 2 * D * D + D * D;
    else if (y == 11) src = We;
    else src = Ow;
    int lane = f & 63, nt = (f >> 6) & 7, s = f >> 9;
    int n = nt * 16 + (lane & 15);
    int ks = s * 32 + (lane >> 4) * 8;
    u16 tmp[8];
#pragma unroll
    for (int j = 0; j < 8; ++j) tmp[j] = f2bs(src[(size_t)(ks + j) * D + n]);
    *(uint4*)&g_WnF[((size_t)(base + y) * 2048 + f) * 8] = *(uint4*)tmp;
}

// ---- node transforms (MFMA, LDS-free): xl (bf16+fp8) / P[r],Q[r] (fp8) ----
__global__ __launch_bounds__(256) void k_node(const float* __restrict__ bl, int wbase) {
    const int tid = threadIdx.x;
    const int n0 = blockIdx.x * 64;
    const int wsel = blockIdx.y;
    const int l = tid & 63, w = tid >> 6;
    const int mrow = l & 15, quad = l >> 4;
    const u16* xrow = g_x + (size_t)(n0 + w * 16 + mrow) * D;
    const u16* BF = g_WnF + (size_t)(wbase + wsel) * 2048 * 8;

    f4v acc[8];
#pragma unroll
    for (int nt = 0; nt < 8; ++nt) acc[nt] = (f4v){0.f, 0.f, 0.f, 0.f};
#pragma unroll
    for (int s = 0; s < 4; ++s) {
        s8v a = *(const s8v*)&xrow[s * 32 + quad * 8];
#pragma unroll
        for (int nt = 0; nt < 8; ++nt) {
            s8v b = *(const s8v*)&BF[(size_t)((s * 8 + nt) * 64 + l) * 8];
            acc[nt] = __builtin_amdgcn_mfma_f32_16x16x32_bf16(a, b, acc[nt], 0, 0, 0);
        }
    }

    if (wsel == 0) {
#pragma unroll
        for (int nt = 0; nt < 8; ++nt) {
            int col = nt * 16 + mrow;
            float bias = bl[col];
            float v[4];
#pragma unroll
            for (int r = 0; r < 4; ++r) v[r] = acc[nt][r] + bias;
#pragma unroll
            for (int r = 0; r < 4; ++r) {
                int row = n0 + w * 16 + quad * 4 + r;
                g_xl[(size_t)row * D + col] = rnd16(v[r]);
            }
#pragma unroll
            for (int r = 0; r < 4; r += 2) {
                u32 pk = __builtin_amdgcn_cvt_pk_fp8_f32(v[r], v[r + 1], 0, false);
                int row = n0 + w * 16 + quad * 4 + r;
                g_xl8[(size_t)row * D + col] = (u8)(pk & 0xffu);
                g_xl8[(size_t)(row + 1) * D + col] = (u8)((pk >> 8) & 0xffu);
            }
        }
    } else {
        u8* out8 = (wsel <= R) ? g_P8 + (size_t)(wsel - 1) * NN * D
                               : g_Q8 + (size_t)(wsel - 1 - R) * NN * D;
#pragma unroll
        for (int nt = 0; nt < 8; ++nt) {
            int col = nt * 16 + mrow;
#pragma unroll
            for (int r = 0; r < 4; r += 2) {
                u32 pk = __builtin_amdgcn_cvt_pk_fp8_f32(acc[nt][r], acc[nt][r + 1], 0, false);
                int row = n0 + w * 16 + quad * 4 + r;
                out8[(size_t)row * D + col] = (u8)(pk & 0xffu);
                out8[(size_t)(row + 1) * D + col] = (u8)((pk >> 8) & 0xffu);
            }
        }
    }
}

// ---- fused edge kernel: 1 tile/wave (r13 shape), fp8 gathers, stores exp(logit) ----
// block = 64 CSR positions (4 waves x 16 edges); grid NE/64
__global__ __launch_bounds__(256) void k_edge(const float* __restrict__ att, int wbase) {
    const int tid = threadIdx.x;
    const int e0 = blockIdx.x * 64;
    const int l = tid & 63, w = tid >> 6;
    const int mrow = l & 15, quad = l >> 4;
    const int myrow = w * 16 + mrow;
    const u16* BF = g_WnF + (size_t)(wbase + 11) * 2048 * 8;

    const int se = g_se[e0 + myrow];
    const int de = g_de[e0 + myrow];
    const int re = g_re[e0 + myrow];

    // identity B-frags: Bev for even nt (k_local == mrow), Bod for odd (== mrow+16)
    union { u32 u[4]; s8v v; } bev, bod;
#pragma unroll
    for (int jp = 0; jp < 4; ++jp) {
        int j0 = quad * 8 + jp * 2, j1 = j0 + 1;
        bev.u[jp] = ((j0 == mrow) ? 0x3F80u : 0u) | ((j1 == mrow) ? 0x3F800000u : 0u);
        bod.u[jp] = ((j0 == mrow + 16) ? 0x3F80u : 0u) | ((j1 == mrow + 16) ? 0x3F800000u : 0u);
    }

    const u8* Prow = g_P8 + ((size_t)re * NN + se) * D;
    const u8* Qrow = g_Q8 + ((size_t)re * NN + de) * D;
    const u8* Xs = g_xl8 + (size_t)se * D;
    const u8* Xd = g_xl8 + (size_t)de * D;
    union { u32 u[4]; s8v v; } af[4], xf[4];
#pragma unroll
    for (int s = 0; s < 4; ++s) {
        int c0 = s * 32 + quad * 8;
        uint2 pu = *(const uint2*)&Prow[c0];
        uint2 qu = *(const uint2*)&Qrow[c0];
        uint2 su = *(const uint2*)&Xs[c0];
        uint2 du = *(const uint2*)&Xd[c0];
        f2v p0 = __builtin_amdgcn_cvt_pk_f32_fp8(pu.x, false);
        f2v p1 = __builtin_amdgcn_cvt_pk_f32_fp8(pu.x, true);
        f2v p2 = __builtin_amdgcn_cvt_pk_f32_fp8(pu.y, false);
        f2v p3 = __builtin_amdgcn_cvt_pk_f32_fp8(pu.y, true);
        f2v q0 = __builtin_amdgcn_cvt_pk_f32_fp8(qu.x, false);
        f2v q1 = __builtin_amdgcn_cvt_pk_f32_fp8(qu.x, true);
        f2v q2 = __builtin_amdgcn_cvt_pk_f32_fp8(qu.y, false);
        f2v q3 = __builtin_amdgcn_cvt_pk_f32_fp8(qu.y, true);
        af[s].u[0] = pack2r(gelu_fast(p0.x + q0.x), gelu_fast(p0.y + q0.y));
        af[s].u[1] = pack2r(gelu_fast(p1.x + q1.x), gelu_fast(p1.y + q1.y));
        af[s].u[2] = pack2r(gelu_fast(p2.x + q2.x), gelu_fast(p2.y + q2.y));
        af[s].u[3] = pack2r(gelu_fast(p3.x + q3.x), gelu_fast(p3.y + q3.y));
        f2v s0 = __builtin_amdgcn_cvt_pk_f32_fp8(su.x, false);
        f2v s1 = __builtin_amdgcn_cvt_pk_f32_fp8(su.x, true);
        f2v s2 = __builtin_amdgcn_cvt_pk_f32_fp8(su.y, false);
        f2v s3 = __builtin_amdgcn_cvt_pk_f32_fp8(su.y, true);
        f2v d0 = __builtin_amdgcn_cvt_pk_f32_fp8(du.x, false);
        f2v d1 = __builtin_amdgcn_cvt_pk_f32_fp8(du.x, true);
        f2v d2 = __builtin_amdgcn_cvt_pk_f32_fp8(du.y, false);
        f2v d3 = __builtin_amdgcn_cvt_pk_f32_fp8(du.y, true);
        xf[s].u[0] = pack2r(s0.x + d0.x, s0.y + d0.y);
        xf[s].u[1] = pack2r(s1.x + d1.x, s1.y + d1.y);
        xf[s].u[2] = pack2r(s2.x + d2.x, s2.y + d2.y);
        xf[s].u[3] = pack2r(s3.x + d3.x, s3.y + d3.y);
    }

    f4v acc[8];
#pragma unroll
    for (int nt = 0; nt < 8; ++nt) acc[nt] = (f4v){0.f, 0.f, 0.f, 0.f};
#pragma unroll
    for (int s = 0; s < 4; ++s) {
#pragma unroll
        for (int nt = 0; nt < 8; ++nt) {
            s8v b = *(const s8v*)&BF[(size_t)((s * 8 + nt) * 64 + l) * 8];
            acc[nt] = __builtin_amdgcn_mfma_f32_16x16x32_bf16(af[s].v, b, acc[nt], 0, 0, 0);
        }
        acc[2 * s]     = __builtin_amdgcn_mfma_f32_16x16x32_bf16(xf[s].v, bev.v, acc[2 * s], 0, 0, 0);
        acc[2 * s + 1] = __builtin_amdgcn_mfma_f32_16x16x32_bf16(xf[s].v, bod.v, acc[2 * s + 1], 0, 0, 0);
    }

    // epilogue in C-layout: edge = w*16 + quad*4 + r, col = nt*16 + mrow
    float hsum[4][4];
#pragma unroll
    for (int r = 0; r < 4; ++r)
#pragma unroll
        for (int h = 0; h < 4; ++h) hsum[r][h] = 0.f;
#pragma unroll
    for (int nt = 0; nt < 8; ++nt) {
        int col = nt * 16 + mrow;
        float av = att[col];
        int h = nt >> 1;
#pragma unroll
        for (int r = 0; r < 4; ++r) {
            float m = acc[nt][r];
            float lr = m > 0.f ? m : 0.2f * m;
            hsum[r][h] = fmaf(lr, av, hsum[r][h]);
        }
    }
#pragma unroll
    for (int r = 0; r < 4; ++r)
#pragma unroll
        for (int h = 0; h < 4; ++h) {
            float v = hsum[r][h];
            v += __shfl_xor(v, 1); v += __shfl_xor(v, 2);
            v += __shfl_xor(v, 4); v += __shfl_xor(v, 8);
            hsum[r][h] = v;
        }
    if ((mrow & 3) == 0) {   // store exp(logit) directly
        int r = mrow >> 2;
        float4 v = make_float4(__expf(fminf(hsum[r][0], 80.f)),
                               __expf(fminf(hsum[r][1], 80.f)),
                               __expf(fminf(hsum[r][2], 80.f)),
                               __expf(fminf(hsum[r][3], 80.f)));
        *(float4*)&g_araw[(size_t)(e0 + w * 16 + quad * 4 + r) * H] = v;
    }
}

// ---- fused gather: single-pass aggregate over pre-computed exp(logit) ----
// one wave per dst; block 256 = 4 dsts; grid NN/4
__global__ __launch_bounds__(256) void k_gath(const float* __restrict__ bias,
                                              int do_gelu) {
    const int lane = threadIdx.x & 63;
    const int d = blockIdx.x * 4 + (threadIdx.x >> 6);
    const int off = g_off[d];
    const int deg = g_off[d + 1] - off;
    const int h = lane >> 4;        // head for cols 2*lane, 2*lane+1

    const int* __restrict__ srcs = g_se + off;
    const float* __restrict__ ar = g_araw + (size_t)off * H + h;
    float a0 = 0.f, a1 = 0.f, dn = 0.f;
    int p = 0;
    for (; p + 4 <= deg; p += 4) {
        int s0 = srcs[p], s1 = srcs[p + 1], s2 = srcs[p + 2], s3 = srcs[p + 3];
        u32 w0 = *(const u32*)&g_xl[(size_t)s0 * D + lane * 2];
        u32 w1 = *(const u32*)&g_xl[(size_t)s1 * D + lane * 2];
        u32 w2 = *(const u32*)&g_xl[(size_t)s2 * D + lane * 2];
        u32 w3 = *(const u32*)&g_xl[(size_t)s3 * D + lane * 2];
        float c0 = ar[(p + 0) * H];
        float c1 = ar[(p + 1) * H];
        float c2 = ar[(p + 2) * H];
        float c3 = ar[(p + 3) * H];
        dn += (c0 + c1) + (c2 + c3);
        a0 = fmaf(bflo(w0), c0, a0); a1 = fmaf(bfhi(w0), c0, a1);
        a0 = fmaf(bflo(w1), c1, a0); a1 = fmaf(bfhi(w1), c1, a1);
        a0 = fmaf(bflo(w2), c2, a0); a1 = fmaf(bfhi(w2), c2, a1);
        a0 = fmaf(bflo(w3), c3, a0); a1 = fmaf(bfhi(w3), c3, a1);
    }
    for (; p < deg; ++p) {
        int s = srcs[p];
        u32 w = *(const u32*)&g_xl[(size_t)s * D + lane * 2];
        float cf = ar[p * H];
        dn += cf;
        a0 = fmaf(bflo(w), cf, a0);
        a1 = fmaf(bfhi(w), cf, a1);
    }
    const float inv = __builtin_amdgcn_rcpf(dn + 1e-16f);
    float v0 = a0 * inv + bias[lane * 2];
    float v1 = a1 * inv + bias[lane * 2 + 1];
    if (do_gelu) { v0 = gelu_f(v0); v1 = gelu_f(v1); }
    ((u32*)g_x)[(size_t)d * (D / 2) + lane] = pack2r(v0, v1);
}

// ---- output head (MFMA, LDS-free): y = x[:BS]@out_w + out_b; LayerNorm ----
__global__ __launch_bounds__(256) void k_head(const float* __restrict__ ob,
                                              const float* __restrict__ g,
                                              const float* __restrict__ b,
                                              float* __restrict__ out) {
    const int tid = threadIdx.x;
    const int r0 = blockIdx.x * 64;
    const int l = tid & 63, w = tid >> 6;
    const int mrow = l & 15, quad = l >> 4;
    const u16* xrow = g_x + (size_t)(r0 + w * 16 + mrow) * D;
    const u16* BF = g_WnF + (size_t)12 * 2048 * 8;

    f4v acc[8];
#pragma unroll
    for (int nt = 0; nt < 8; ++nt) acc[nt] = (f4v){0.f, 0.f, 0.f, 0.f};
#pragma unroll
    for (int s = 0; s < 4; ++s) {
        s8v a = *(const s8v*)&xrow[s * 32 + quad * 8];
#pragma unroll
        for (int nt = 0; nt < 8; ++nt) {
            s8v bb = *(const s8v*)&BF[(size_t)((s * 8 + nt) * 64 + l) * 8];
            acc[nt] = __builtin_amdgcn_mfma_f32_16x16x32_bf16(a, bb, acc[nt], 0, 0, 0);
        }
    }

    float sum[4] = {0.f, 0.f, 0.f, 0.f};
#pragma unroll
    for (int nt = 0; nt < 8; ++nt) {
        float obv = ob[nt * 16 + mrow];
#pragma unroll
        for (int r = 0; r < 4; ++r) {
            acc[nt][r] += obv;
            sum[r] += acc[nt][r];
        }
    }
    float mu[4];
#pragma unroll
    for (int r = 0; r < 4; ++r) {
        float s = sum[r];
        s += __shfl_xor(s, 1); s += __shfl_xor(s, 2);
        s += __shfl_xor(s, 4); s += __shfl_xor(s, 8);
        mu[r] = s * (1.f / D);
    }
    float sq[4] = {0.f, 0.f, 0.f, 0.f};
#pragma unroll
    for (int nt = 0; nt < 8; ++nt)
#pragma unroll
        for (int r = 0; r < 4; ++r) {
            float dv = acc[nt][r] - mu[r];
            sq[r] += dv * dv;
        }
    float rs[4];
#pragma unroll
    for (int r = 0; r < 4; ++r) {
        float s = sq[r];
        s += __shfl_xor(s, 1); s += __shfl_xor(s, 2);
        s += __shfl_xor(s, 4); s += __shfl_xor(s, 8);
        rs[r] = rsqrtf(s * (1.f / D) + 1e-12f);
    }
#pragma unroll
    for (int nt = 0; nt < 8; ++nt) {
        int col = nt * 16 + mrow;
        float gv = g[col], bv = b[col];
#pragma unroll
        for (int r = 0; r < 4; ++r) {
            int row = r0 + w * 16 + quad * 4 + r;
            out[(size_t)row * D + col] = (acc[nt][r] - mu[r]) * rs[r] * gv + bv;
        }
    }
}

extern "C" void kernel_launch(void* const* d_in, const int* in_sizes, int n_in,
                              void* d_out, int out_size, void* d_ws, size_t ws_size,
                              hipStream_t stream) {
    (void)in_sizes; (void)n_in; (void)out_size; (void)d_ws; (void)ws_size;
    const float* embs = (const float*)d_in[0];
    const int*   ei   = (const int*)d_in[1];
    const int*   et   = (const int*)d_in[2];
    const float* rel  = (const float*)d_in[3];
    const float* wl[2]   = { (const float*)d_in[4],  (const float*)d_in[9]  };
    const float* bl[2]   = { (const float*)d_in[5],  (const float*)d_in[10] };
    const float* we[2]   = { (const float*)d_in[6],  (const float*)d_in[11] };
    const float* attw[2] = { (const float*)d_in[7],  (const float*)d_in[12] };
    const float* bs[2]   = { (const float*)d_in[8],  (const float*)d_in[13] };
    const float* ow  = (const float*)d_in[14];
    const float* ob  = (const float*)d_in[15];
    const float* lng = (const float*)d_in[16];
    const float* lnb = (const float*)d_in[17];
    float* out = (float*)d_out;

    k_cvt<<<NN * D / 512, 256, 0, stream>>>(embs);

    // weight prep for BOTH layers up front (overlaps CSR build)
    for (int l = 0; l < 2; ++l) {
        const float* Rm = rel + (size_t)l * R * 2 * D * D;
        k_prep<<<dim3(2048 / 256, 13), 256, 0, stream>>>(wl[l], Rm, we[l], ow, l * 13);
    }

    // CSR by dst (edge list shared by both layers)
    k_zcnt<<<NN / 256, 256, 0, stream>>>();
    k_count<<<NE / 256, 256, 0, stream>>>(ei);
    k_scan<<<1, 1024, 0, stream>>>();
    k_scatter<<<NE / 256, 256, 0, stream>>>(ei, et);

    for (int l = 0; l < 2; ++l) {
        k_node<<<dim3(NN / 64, 11), 256, 0, stream>>>(bl[l], l * 13);
        k_edge<<<NE / 64, 256, 0, stream>>>(attw[l], l * 13);
        k_gath<<<NN / 4, 256, 0, stream>>>(bs[l], l == 0 ? 1 : 0);
    }

    k_head<<<BS / 64, 256, 0, stream>>>(ob, lng, lnb, out);
}